// Round 5
// baseline (212.943 us; speedup 1.0000x reference)
//
#include <hip/hip_runtime.h>
#include <hip/hip_fp16.h>

// Quant4Linear + EoRA fused GEMV, MI355X — single-kernel, zero-workspace.
//
// y[n] = bias[n] + scales[n]*sum_k x[k]*q[k,n] - zeros[n]*Sx + sum_r fp16(dp[r])*up[r,n]
//   q = nibble unpack of qweight (K/8 x N int32), dp = half(x) @ down.
//
// Round-5 forensics: the only theory consistent with ALL prior rounds is that
// the harness delivers the reference's fp16 tensors (down, up) as FLOAT32
// buffers (its ABI supports only bf16/fp32/int):
//  - r1 (fp16 decode of fp32 buffer): lo-half ushorts have 13 zero pad bits ->
//    decode <= 2^9, never NaN -> finite garbage ~5e7 (observed 1.7e8) OK
//  - r2-4 (detector votes bf16 on fp32 buffer): lo-halves decode up to 2^65 ->
//    dp overflow -> __float2half = Inf -> Inf*0 = NaN (observed) OK
//  - npz size 123.37 MB matches fp32 down/up (13-zero-mantissa, deflates) OK
// Values in those buffers are already fp16-rounded, matching the reference's
// fp16 semantics. A tri-mode runtime detector (fp32-carrier / bf16 / fp16)
// guards against the remaining uncertainty; detection of the fp32 carrier is
// exact via the 13-zero-bit signature.

#define KDIM 8192
#define NDIM 28672
#define RDIM 64

#define KCHUNKS 32
#define KPC (KDIM / KCHUNKS)      // 256 k per quant chunk
#define KBPC (KPC / 8)            // 32 packed rows per chunk
#define CPB 1024                  // 256 threads x 4 cols
#define NBLK (NDIM / CPB)         // 28

// mode: 0 = fp32 carrier, 1 = bf16, 2 = fp16
__device__ inline int detect_mode(const void* __restrict__ p) {
    const unsigned short* u = (const unsigned short*)p;
    int lozero = 0;
    for (int i = 0; i < 64; i += 2) {
        if ((u[i] & 0x1FFFu) == 0u) ++lozero;   // fp16->fp32 pads 13 zero bits
    }
    if (lozero >= 24) return 0;
    int bf = 0, fp = 0;
    for (int i = 0; i < 64; ++i) {
        const unsigned short v = u[i];
        if ((v & 0x7FFFu) == 0u) continue;
        const int e5 = (v >> 10) & 0x1F;
        if (e5 >= 13) ++bf; else ++fp;
    }
    return (bf >= fp) ? 1 : 2;
}

__device__ inline float load16(const void* __restrict__ p, size_t idx, int mode) {
    if (mode == 0) return ((const float*)p)[idx];
    const unsigned short v = ((const unsigned short*)p)[idx];
    if (mode == 1) return __uint_as_float(((unsigned)v) << 16);
    __half h;
    *reinterpret_cast<unsigned short*>(&h) = v;
    return __half2float(h);
}

__global__ __launch_bounds__(256) void fused_kernel(const float* __restrict__ x,
                                                    const int* __restrict__ qw,
                                                    const float* __restrict__ scales,
                                                    const float* __restrict__ zeros,
                                                    const float* __restrict__ bias,
                                                    const void* __restrict__ down,
                                                    const void* __restrict__ up,
                                                    float* __restrict__ out) {
    const int t  = threadIdx.x;
    const int ph = blockIdx.y;
    const int n0 = blockIdx.x * CPB + t * 4;

    if (ph < KCHUNKS) {
        // ------------- quant chunk: k in [ph*256, ph*256+256) -------------
        __shared__ __align__(16) float xs[KPC];
        __shared__ float sxs;
        if (t < KPC / 4) {
            *(float4*)&xs[t * 4] = *(const float4*)&x[ph * KPC + t * 4];
        }
        __syncthreads();
        if (t < 64) {
            float s = xs[t * 4] + xs[t * 4 + 1] + xs[t * 4 + 2] + xs[t * 4 + 3];
            #pragma unroll
            for (int o = 32; o >= 1; o >>= 1) s += __shfl_down(s, o, 64);
            if (t == 0) sxs = s;
        }
        __syncthreads();
        const float Sxc = sxs;

        float a0 = 0.f, a1 = 0.f, a2 = 0.f, a3 = 0.f;
        const int* qp = qw + (size_t)(ph * KBPC) * NDIM + n0;
        for (int kb = 0; kb < KBPC; ++kb) {
            const int4 wv = *(const int4*)qp;
            qp += NDIM;
            const unsigned wx = (unsigned)wv.x, wy = (unsigned)wv.y;
            const unsigned wz = (unsigned)wv.z, ww = (unsigned)wv.w;
            const float* xr = &xs[kb * 8];
            #pragma unroll
            for (int j = 0; j < 8; ++j) {
                const float xj = xr[j];
                a0 = fmaf(xj, (float)((wx >> (4 * j)) & 0xFu), a0);
                a1 = fmaf(xj, (float)((wy >> (4 * j)) & 0xFu), a1);
                a2 = fmaf(xj, (float)((wz >> (4 * j)) & 0xFu), a2);
                a3 = fmaf(xj, (float)((ww >> (4 * j)) & 0xFu), a3);
            }
        }

        const float4 sc = *(const float4*)&scales[n0];
        const float4 zr = *(const float4*)&zeros[n0];
        float p0 = fmaf(sc.x, a0, -zr.x * Sxc);
        float p1 = fmaf(sc.y, a1, -zr.y * Sxc);
        float p2 = fmaf(sc.z, a2, -zr.z * Sxc);
        float p3 = fmaf(sc.w, a3, -zr.w * Sxc);
        if (ph == 0) {
            const float4 bi = *(const float4*)&bias[n0];
            p0 += bi.x; p1 += bi.y; p2 += bi.z; p3 += bi.w;
        }
        atomicAdd(&out[n0 + 0], p0);
        atomicAdd(&out[n0 + 1], p1);
        atomicAdd(&out[n0 + 2], p2);
        atomicAdd(&out[n0 + 3], p3);
    } else {
        // ------------- EoRA: full-K dp in-block, then dp16 @ up -----------
        const int mode = detect_mode(down);
        const int r  = t & 63;
        const int w  = t >> 6;                 // 4 waves, k-stripes of 2048
        const int k0 = w * (KDIM / 4);

        float acc0 = 0.f, acc1 = 0.f;
        for (int k = k0; k < k0 + KDIM / 4; k += 2) {
            const float xv0 = __half2float(__float2half(x[k]));      // xh = x.half()
            const float xv1 = __half2float(__float2half(x[k + 1]));
            acc0 = fmaf(xv0, load16(down, (size_t)k * RDIM + r, mode), acc0);
            acc1 = fmaf(xv1, load16(down, (size_t)(k + 1) * RDIM + r, mode), acc1);
        }
        __shared__ float part[4][64];
        part[w][r] = acc0 + acc1;
        __syncthreads();
        __shared__ float dp[RDIM];
        if (t < 64) {
            const float d = part[0][t] + part[1][t] + part[2][t] + part[3][t];
            dp[t] = __half2float(__float2half(d));   // down_proj is fp16 in ref
        }
        __syncthreads();

        float e0 = 0.f, e1 = 0.f, e2 = 0.f, e3 = 0.f;
        if (mode == 0) {
            const float* upf = (const float*)up;
            #pragma unroll 8
            for (int rr = 0; rr < RDIM; ++rr) {
                const float d = dp[rr];
                const float4 uv = *(const float4*)&upf[(size_t)rr * NDIM + n0];
                e0 = fmaf(d, uv.x, e0);
                e1 = fmaf(d, uv.y, e1);
                e2 = fmaf(d, uv.z, e2);
                e3 = fmaf(d, uv.w, e3);
            }
        } else {
            #pragma unroll 8
            for (int rr = 0; rr < RDIM; ++rr) {
                const float d = dp[rr];
                const size_t ub = (size_t)rr * NDIM + n0;
                e0 = fmaf(d, load16(up, ub + 0, mode), e0);
                e1 = fmaf(d, load16(up, ub + 1, mode), e1);
                e2 = fmaf(d, load16(up, ub + 2, mode), e2);
                e3 = fmaf(d, load16(up, ub + 3, mode), e3);
            }
        }
        atomicAdd(&out[n0 + 0], e0);
        atomicAdd(&out[n0 + 1], e1);
        atomicAdd(&out[n0 + 2], e2);
        atomicAdd(&out[n0 + 3], e3);
    }
}

extern "C" void kernel_launch(void* const* d_in, const int* in_sizes, int n_in,
                              void* d_out, int out_size, void* d_ws, size_t ws_size,
                              hipStream_t stream) {
    const float* x      = (const float*)d_in[0];
    const int*   qw     = (const int*)d_in[1];
    const float* scales = (const float*)d_in[2];
    const float* zeros  = (const float*)d_in[3];
    const float* bias   = (const float*)d_in[4];
    const void*  down   = d_in[5];   // (K, R)  fp16 values in fp32 carrier (detected)
    const void*  up     = d_in[6];   // (R, N)  fp16 values in fp32 carrier (detected)
    float* out = (float*)d_out;
    (void)d_ws; (void)ws_size;

    hipMemsetAsync(out, 0, (size_t)NDIM * sizeof(float), stream);
    fused_kernel<<<dim3(NBLK, KCHUNKS + 1), 256, 0, stream>>>(
        x, qw, scales, zeros, bias, down, up, out);
}

// Round 6
// 43.817 us; speedup vs baseline: 4.8598x; 4.8598x over previous
//
#include <hip/hip_runtime.h>
#include <hip/hip_fp16.h>

// Quant4Linear + EoRA fused GEMV, MI355X.
// y[n] = bias[n] + scales[n]*sum_k x[k]*q[k,n] - zeros[n]*Sx + sum_r fp16(dp[r])*up[r,n]
//   q = nibble unpack of qweight (K/8 x N int32), dp = half(x) @ down.
//
// PROVEN (round 5 pass, absmax 0.0625): harness delivers the fp16 tensors
// (down, up) as FLOAT32 buffers; d_in is dict-order; out is fp32.
// Round 5 counters: 283 us, VALUBusy 6.9%, HBM 252 GB/s (3%), occupancy 7.7%
// -> pure latency-bound. This round: (1) quant loop batches 4 independent
// int4 loads per iteration (4 in flight/thread); (2) EoRA dp moved to a tiny
// prep kernel with wave-transposed coalesced float4 reads of down, partials
// in d_ws via plain stores; (3) up-rows distributed 2-per-chunk across the
// quant blocks (no dedicated EoRA blocks, no redundant full-K dp).

#define KDIM 8192
#define NDIM 28672
#define RDIM 64

#define KCHUNKS 32
#define KPC (KDIM / KCHUNKS)      // 256 k per quant chunk
#define KBPC (KPC / 8)            // 32 packed rows per chunk
#define CPB 1024                  // 256 threads x 4 cols
#define NBLK (NDIM / CPB)         // 28

#define PB 8                      // prep blocks
#define PKPB (KDIM / PB)          // 1024 k per prep block
#define WS_NEED (PB * RDIM * 4)   // 2048 bytes of d_ws

// ---------------------------------------------------------------------------
// prep: dp partials. Block b covers k in [b*1024, (b+1)*1024).
// Wave-transposed layout: one float4 per lane covers 4 consecutive rows of
// down (row = 256B), so each wave load is 1KB contiguous. 4 loads in flight.
// ws[b*64 + r] = sum_{k in block} half(x[k]) * down[k][r]   (plain stores)
// ---------------------------------------------------------------------------
__global__ __launch_bounds__(256) void prep_kernel(const float* __restrict__ x,
                                                   const float* __restrict__ down,
                                                   float* __restrict__ ws) {
    const int b = blockIdx.x;
    const int t = threadIdx.x;
    const int w = t >> 6;          // wave 0..3
    const int l = t & 63;
    const int grp = l >> 4;        // which of 4 rows in the quad this lane holds
    const int li = l & 15;         // float4 slot within the row (r = li*4..li*4+3)

    __shared__ float xs[PKPB];     // fp16-rounded x chunk (dp uses xh)
    {
        float4 v = *(const float4*)&x[b * PKPB + t * 4];
        v.x = __half2float(__float2half(v.x));
        v.y = __half2float(__float2half(v.y));
        v.z = __half2float(__float2half(v.z));
        v.w = __half2float(__float2half(v.w));
        *(float4*)&xs[t * 4] = v;
    }
    __syncthreads();

    // quad q (rows 4q..4q+3) for q = i+u)*4+w; lane l reads
    // down[(4q+grp)*64 + li*4 ..] = dbase[q*256 + l*4 ..]
    const float* dbase = down + (size_t)b * PKPB * RDIM;
    float a0 = 0.f, a1 = 0.f, a2 = 0.f, a3 = 0.f;
    for (int i = 0; i < 64; i += 4) {
        float4 v[4];
        #pragma unroll
        for (int u = 0; u < 4; ++u) {
            const int q = (i + u) * 4 + w;
            v[u] = *(const float4*)&dbase[(size_t)q * 256 + l * 4];
        }
        #pragma unroll
        for (int u = 0; u < 4; ++u) {
            const int q = (i + u) * 4 + w;
            const float xv = xs[q * 4 + grp];
            a0 = fmaf(xv, v[u].x, a0);
            a1 = fmaf(xv, v[u].y, a1);
            a2 = fmaf(xv, v[u].z, a2);
            a3 = fmaf(xv, v[u].w, a3);
        }
    }

    // reduce over the 4 row-groups (lanes l, l^16, l^32, l^48 share r-set)
    a0 += __shfl_xor(a0, 16, 64); a0 += __shfl_xor(a0, 32, 64);
    a1 += __shfl_xor(a1, 16, 64); a1 += __shfl_xor(a1, 32, 64);
    a2 += __shfl_xor(a2, 16, 64); a2 += __shfl_xor(a2, 32, 64);
    a3 += __shfl_xor(a3, 16, 64); a3 += __shfl_xor(a3, 32, 64);

    __shared__ float part[4][RDIM];
    if (l < 16) {
        part[w][li * 4 + 0] = a0;
        part[w][li * 4 + 1] = a1;
        part[w][li * 4 + 2] = a2;
        part[w][li * 4 + 3] = a3;
    }
    __syncthreads();
    if (t < RDIM) {
        ws[b * RDIM + t] = part[0][t] + part[1][t] + part[2][t] + part[3][t];
    }
}

// ---------------------------------------------------------------------------
// main: grid (28, 32) x 256. Block (cx, ph): cols n0 = cx*1024 + t*4,
// k in [ph*256, ph*256+256), up-rows {2ph, 2ph+1}. 4 int4 loads in flight.
// ---------------------------------------------------------------------------
__global__ __launch_bounds__(256) void gemv_eora_kernel(const float* __restrict__ x,
                                                        const int* __restrict__ qw,
                                                        const float* __restrict__ scales,
                                                        const float* __restrict__ zeros,
                                                        const float* __restrict__ bias,
                                                        const float* __restrict__ upf,
                                                        const float* __restrict__ ws,
                                                        float* __restrict__ out) {
    const int t  = threadIdx.x;
    const int ph = blockIdx.y;
    const int n0 = blockIdx.x * CPB + t * 4;

    __shared__ __align__(16) float xs[KPC];
    __shared__ float dps[RDIM];
    __shared__ float sxs;

    if (t < KPC / 4) {                       // 64 threads load x chunk (raw fp32)
        *(float4*)&xs[t * 4] = *(const float4*)&x[ph * KPC + t * 4];
    } else if (t < KPC / 4 + RDIM) {         // 64 threads sum dp partials
        const int r = t - KPC / 4;
        float d = 0.f;
        #pragma unroll
        for (int b = 0; b < PB; ++b) d += ws[b * RDIM + r];
        dps[r] = __half2float(__float2half(d));   // down_proj is fp16 in ref
    }
    __syncthreads();
    if (t < 64) {
        float s = xs[t * 4] + xs[t * 4 + 1] + xs[t * 4 + 2] + xs[t * 4 + 3];
        #pragma unroll
        for (int o = 32; o >= 1; o >>= 1) s += __shfl_down(s, o, 64);
        if (t == 0) sxs = s;
    }
    __syncthreads();
    const float Sxc = sxs;

    float a0 = 0.f, a1 = 0.f, a2 = 0.f, a3 = 0.f;
    const int* qp = qw + (size_t)(ph * KBPC) * NDIM + n0;
    for (int g = 0; g < KBPC; g += 4) {
        int4 wv[4];
        #pragma unroll
        for (int u = 0; u < 4; ++u) {
            wv[u] = *(const int4*)(qp + (size_t)u * NDIM);
        }
        qp += 4 * (size_t)NDIM;
        #pragma unroll
        for (int u = 0; u < 4; ++u) {
            const unsigned wx = (unsigned)wv[u].x, wy = (unsigned)wv[u].y;
            const unsigned wz = (unsigned)wv[u].z, ww = (unsigned)wv[u].w;
            const float* xr = &xs[(g + u) * 8];
            #pragma unroll
            for (int j = 0; j < 8; ++j) {
                const float xj = xr[j];
                a0 = fmaf(xj, (float)((wx >> (4 * j)) & 0xFu), a0);
                a1 = fmaf(xj, (float)((wy >> (4 * j)) & 0xFu), a1);
                a2 = fmaf(xj, (float)((wz >> (4 * j)) & 0xFu), a2);
                a3 = fmaf(xj, (float)((ww >> (4 * j)) & 0xFu), a3);
            }
        }
    }

    // EoRA slice: up rows 2ph, 2ph+1 (fp32 carrier, values fp16-rounded)
    float e0 = 0.f, e1 = 0.f, e2 = 0.f, e3 = 0.f;
    #pragma unroll
    for (int rr = 0; rr < 2; ++rr) {
        const int r = ph * 2 + rr;
        const float d = dps[r];
        const float4 uv = *(const float4*)&upf[(size_t)r * NDIM + n0];
        e0 = fmaf(d, uv.x, e0);
        e1 = fmaf(d, uv.y, e1);
        e2 = fmaf(d, uv.z, e2);
        e3 = fmaf(d, uv.w, e3);
    }

    const float4 sc = *(const float4*)&scales[n0];
    const float4 zr = *(const float4*)&zeros[n0];
    float p0 = fmaf(sc.x, a0, e0) - zr.x * Sxc;
    float p1 = fmaf(sc.y, a1, e1) - zr.y * Sxc;
    float p2 = fmaf(sc.z, a2, e2) - zr.z * Sxc;
    float p3 = fmaf(sc.w, a3, e3) - zr.w * Sxc;
    if (ph == 0) {
        const float4 bi = *(const float4*)&bias[n0];
        p0 += bi.x; p1 += bi.y; p2 += bi.z; p3 += bi.w;
    }
    atomicAdd(&out[n0 + 0], p0);
    atomicAdd(&out[n0 + 1], p1);
    atomicAdd(&out[n0 + 2], p2);
    atomicAdd(&out[n0 + 3], p3);
}

// ---------------------------------------------------------------------------
// Fallback (round-5 passing kernel, zero-workspace) in case ws_size < 2KB.
// ---------------------------------------------------------------------------
__global__ __launch_bounds__(256) void fused_fallback(const float* __restrict__ x,
                                                      const int* __restrict__ qw,
                                                      const float* __restrict__ scales,
                                                      const float* __restrict__ zeros,
                                                      const float* __restrict__ bias,
                                                      const float* __restrict__ down,
                                                      const float* __restrict__ up,
                                                      float* __restrict__ out) {
    const int t  = threadIdx.x;
    const int ph = blockIdx.y;
    const int n0 = blockIdx.x * CPB + t * 4;

    if (ph < KCHUNKS) {
        __shared__ __align__(16) float xs[KPC];
        __shared__ float sxs;
        if (t < KPC / 4) {
            *(float4*)&xs[t * 4] = *(const float4*)&x[ph * KPC + t * 4];
        }
        __syncthreads();
        if (t < 64) {
            float s = xs[t * 4] + xs[t * 4 + 1] + xs[t * 4 + 2] + xs[t * 4 + 3];
            #pragma unroll
            for (int o = 32; o >= 1; o >>= 1) s += __shfl_down(s, o, 64);
            if (t == 0) sxs = s;
        }
        __syncthreads();
        const float Sxc = sxs;
        float a0 = 0.f, a1 = 0.f, a2 = 0.f, a3 = 0.f;
        const int* qp = qw + (size_t)(ph * KBPC) * NDIM + n0;
        for (int kb = 0; kb < KBPC; ++kb) {
            const int4 wv = *(const int4*)qp;
            qp += NDIM;
            const unsigned wx = (unsigned)wv.x, wy = (unsigned)wv.y;
            const unsigned wz = (unsigned)wv.z, ww = (unsigned)wv.w;
            const float* xr = &xs[kb * 8];
            #pragma unroll
            for (int j = 0; j < 8; ++j) {
                const float xj = xr[j];
                a0 = fmaf(xj, (float)((wx >> (4 * j)) & 0xFu), a0);
                a1 = fmaf(xj, (float)((wy >> (4 * j)) & 0xFu), a1);
                a2 = fmaf(xj, (float)((wz >> (4 * j)) & 0xFu), a2);
                a3 = fmaf(xj, (float)((ww >> (4 * j)) & 0xFu), a3);
            }
        }
        const float4 sc = *(const float4*)&scales[n0];
        const float4 zr = *(const float4*)&zeros[n0];
        float p0 = fmaf(sc.x, a0, -zr.x * Sxc);
        float p1 = fmaf(sc.y, a1, -zr.y * Sxc);
        float p2 = fmaf(sc.z, a2, -zr.z * Sxc);
        float p3 = fmaf(sc.w, a3, -zr.w * Sxc);
        if (ph == 0) {
            const float4 bi = *(const float4*)&bias[n0];
            p0 += bi.x; p1 += bi.y; p2 += bi.z; p3 += bi.w;
        }
        atomicAdd(&out[n0 + 0], p0);
        atomicAdd(&out[n0 + 1], p1);
        atomicAdd(&out[n0 + 2], p2);
        atomicAdd(&out[n0 + 3], p3);
    } else {
        const int r  = t & 63;
        const int w  = t >> 6;
        const int k0 = w * (KDIM / 4);
        float acc0 = 0.f, acc1 = 0.f;
        for (int k = k0; k < k0 + KDIM / 4; k += 2) {
            const float xv0 = __half2float(__float2half(x[k]));
            const float xv1 = __half2float(__float2half(x[k + 1]));
            acc0 = fmaf(xv0, down[(size_t)k * RDIM + r], acc0);
            acc1 = fmaf(xv1, down[(size_t)(k + 1) * RDIM + r], acc1);
        }
        __shared__ float part[4][64];
        part[w][r] = acc0 + acc1;
        __syncthreads();
        __shared__ float dp[RDIM];
        if (t < 64) {
            const float d = part[0][t] + part[1][t] + part[2][t] + part[3][t];
            dp[t] = __half2float(__float2half(d));
        }
        __syncthreads();
        float e0 = 0.f, e1 = 0.f, e2 = 0.f, e3 = 0.f;
        #pragma unroll 8
        for (int rr = 0; rr < RDIM; ++rr) {
            const float d = dp[rr];
            const float4 uv = *(const float4*)&up[(size_t)rr * NDIM + n0];
            e0 = fmaf(d, uv.x, e0);
            e1 = fmaf(d, uv.y, e1);
            e2 = fmaf(d, uv.z, e2);
            e3 = fmaf(d, uv.w, e3);
        }
        atomicAdd(&out[n0 + 0], e0);
        atomicAdd(&out[n0 + 1], e1);
        atomicAdd(&out[n0 + 2], e2);
        atomicAdd(&out[n0 + 3], e3);
    }
}

extern "C" void kernel_launch(void* const* d_in, const int* in_sizes, int n_in,
                              void* d_out, int out_size, void* d_ws, size_t ws_size,
                              hipStream_t stream) {
    const float* x      = (const float*)d_in[0];
    const int*   qw     = (const int*)d_in[1];
    const float* scales = (const float*)d_in[2];
    const float* zeros  = (const float*)d_in[3];
    const float* bias   = (const float*)d_in[4];
    const float* down   = (const float*)d_in[5];   // fp16 values in fp32 carrier (proven r5)
    const float* up     = (const float*)d_in[6];   // fp16 values in fp32 carrier (proven r5)
    float* out = (float*)d_out;
    float* ws  = (float*)d_ws;

    hipMemsetAsync(out, 0, (size_t)NDIM * sizeof(float), stream);
    if (ws_size >= WS_NEED) {
        prep_kernel<<<PB, 256, 0, stream>>>(x, down, ws);
        gemv_eora_kernel<<<dim3(NBLK, KCHUNKS), 256, 0, stream>>>(
            x, qw, scales, zeros, bias, up, ws, out);
    } else {
        fused_fallback<<<dim3(NBLK, KCHUNKS + 1), 256, 0, stream>>>(
            x, qw, scales, zeros, bias, down, up, out);
    }
}